// Round 12
// baseline (507.262 us; speedup 1.0000x reference)
//
#include <hip/hip_runtime.h>

#define DIM 1536
#define NH 12
#define HD 128
#define KSPLIT 8
#define KT 32
#define MFIX 3.0f
#define KK48 48   // DIM/32 K-steps

typedef _Float16 half2_t __attribute__((ext_vector_type(2)));
typedef _Float16 half8_t __attribute__((ext_vector_type(8)));
typedef float f32x4 __attribute__((ext_vector_type(4)));

__device__ __forceinline__ half2_t pkrtz(float a, float b) {
    return __builtin_bit_cast(half2_t, __builtin_amdgcn_cvt_pkrtz(a, b));
}

__device__ __forceinline__ void split8(float4 a, float4 b, half8_t& h, half8_t& l) {
    half2_t h0 = pkrtz(a.x, a.y), h1 = pkrtz(a.z, a.w);
    half2_t h2 = pkrtz(b.x, b.y), h3 = pkrtz(b.z, b.w);
    half2_t g0 = pkrtz(a.x - (float)h0.x, a.y - (float)h0.y);
    half2_t g1 = pkrtz(a.z - (float)h1.x, a.w - (float)h1.y);
    half2_t g2 = pkrtz(b.x - (float)h2.x, b.y - (float)h2.y);
    half2_t g3 = pkrtz(b.z - (float)h3.x, b.w - (float)h3.y);
    h[0]=h0.x; h[1]=h0.y; h[2]=h1.x; h[3]=h1.y; h[4]=h2.x; h[5]=h2.y; h[6]=h3.x; h[7]=h3.y;
    l[0]=g0.x; l[1]=g0.y; l[2]=g1.x; l[3]=g1.y; l[4]=g2.x; l[5]=g2.y; l[6]=g3.x; l[7]=g3.y;
}

// hi-only pkrtz conversion (bit-identical to split8's h output)
__device__ __forceinline__ half8_t hi8(float4 a, float4 b) {
    half2_t h0 = pkrtz(a.x, a.y), h1 = pkrtz(a.z, a.w);
    half2_t h2 = pkrtz(b.x, b.y), h3 = pkrtz(b.z, b.w);
    half8_t h;
    h[0]=h0.x; h[1]=h0.y; h[2]=h1.x; h[3]=h1.y; h[4]=h2.x; h[5]=h2.y; h[6]=h3.x; h[7]=h3.y;
    return h;
}

// round-to-nearest f32x8 -> f16x8 (attention Q/K single-precision path)
__device__ __forceinline__ half8_t cvt8rn(float4 a, float4 b) {
    half8_t h;
    h[0]=(_Float16)a.x; h[1]=(_Float16)a.y; h[2]=(_Float16)a.z; h[3]=(_Float16)a.w;
    h[4]=(_Float16)b.x; h[5]=(_Float16)b.y; h[6]=(_Float16)b.z; h[7]=(_Float16)b.w;
    return h;
}

// async global->LDS, 16 B per lane; lds must be wave-uniform, HW adds lane*16
__device__ __forceinline__ void gl2lds16(const void* g, void* l) {
    __builtin_amdgcn_global_load_lds(
        (const __attribute__((address_space(1))) unsigned int*)g,
        (__attribute__((address_space(3))) unsigned int*)(unsigned int)(uintptr_t)l,
        16, 0, 0);
}

// ===== MFMA-frag-linear tile records =====
// A 128x32 (rows x k) f16 tile stored as rec[grp(8)][lane(64)][j(8)]:
//   row = grp*16 + (lane&15), k = (lane>>4)*8 + j  (4096 halfs = 8 KB).

// ---------------- 4 weight matrices -> frag-linear hi/lo B-records ----------
// lo-halves only written for v (m=2) and wo (m=3): q,k run single-pass.
__global__ __launch_bounds__(256) void cvt_w_fl(
    const float* __restrict__ s0, const float* __restrict__ s1,
    const float* __restrict__ s2, const float* __restrict__ s3,
    _Float16* __restrict__ h0, _Float16* __restrict__ l0,
    _Float16* __restrict__ h1, _Float16* __restrict__ l1,
    _Float16* __restrict__ h2, _Float16* __restrict__ l2,
    _Float16* __restrict__ h3, _Float16* __restrict__ l3, int nrec8)
{
    const int i = blockIdx.x * 256 + threadIdx.x;
    if (i >= nrec8) return;
    const int m = blockIdx.y;
    const float* src = m == 0 ? s0 : m == 1 ? s1 : m == 2 ? s2 : s3;
    _Float16* h = m == 0 ? h0 : m == 1 ? h1 : m == 2 ? h2 : h3;
    _Float16* l = m == 0 ? l0 : m == 1 ? l1 : m == 2 ? l2 : l3;
    const int lane = i & 63;
    const int grp  = (i >> 6) & 7;
    const int tile = i >> 9;                  // nt*KK48 + kk
    const int kk = tile % KK48, nt = tile / KK48;
    const int row = nt * 128 + grp * 16 + (lane & 15);
    const int k   = kk * 32 + (lane >> 4) * 8;
    const float* s = src + (size_t)row * DIM + k;
    float4 a = *(const float4*)s, b = *(const float4*)(s + 4);
    half8_t hh, ll; split8(a, b, hh, ll);
    ((half8_t*)h)[i] = hh;
    if (m >= 2) ((half8_t*)l)[i] = ll;
}

// ---------------- single-pass fp16 GEMM (q,k), direct f32-A staging ---------
// A is staged straight from x: reg-load float4s for K-step kk+1 early, then
// vmcnt(0) + pkrtz-hi + ds_write_b128 after the MFMA phase (T14 split). This
// removed the cvt_a kernel (dispatch + 29 MB roundtrip); bytes identical
// (f32 = hi+lo f16). B stays gl2lds from pre-converted records. 32 KB LDS.
__global__ __launch_bounds__(256, 4) void gemm_fl_s(
    const float* __restrict__ X,
    const _Float16* __restrict__ Bh0, const _Float16* __restrict__ Bh1,
    const float* __restrict__ bias0, const float* __restrict__ bias1,
    float* __restrict__ C0, float* __restrict__ C1,
    int M)
{
    __shared__ __align__(16) _Float16 T[2][2][4096];   // Ah, Bh tiles

    const int nwg = gridDim.x;               // 24*MT
    const int L = blockIdx.x;
    const int q8 = nwg >> 3, r8 = nwg & 7;
    const int xcd = L & 7, si = L >> 3;
    const int logical = (xcd < r8 ? xcd * (q8 + 1)
                                  : r8 * (q8 + 1) + (xcd - r8) * q8) + si;
    const int j   = logical % 24;            // q/k interleaved, A-tile shared
    const int myy = logical / 24;
    const int mat = j & 1, nt = j >> 1;
    const _Float16* Bh   = mat ? Bh1 : Bh0;
    const float*    bias = mat ? bias1 : bias0;
    float*          C    = mat ? C1 : C0;
    const int m0 = myy * 128, n0 = nt * 128;

    const int tid = threadIdx.x;
    const int lane = tid & 63, wave = tid >> 6;
    const int l16 = lane & 15, quad = lane >> 4;
    const int wm = (wave >> 1) * 64, wn = (wave & 1) * 64;

    // this thread's two A half8 record slots
    const int i0 = tid * 2;
    const int g0 = i0 >> 6,     lr0 = i0 & 63;
    const int g1 = (i0+1) >> 6, lr1 = (i0+1) & 63;
    const int row0 = m0 + g0 * 16 + (lr0 & 15);
    const int row1 = m0 + g1 * 16 + (lr1 & 15);
    const bool r0v = row0 < M, r1v = row1 < M;
    const float* x0 = X + (size_t)(r0v ? row0 : 0) * DIM + (lr0 >> 4) * 8;
    const float* x1 = X + (size_t)(r1v ? row1 : 0) * DIM + (lr1 >> 4) * 8;

    const _Float16* Brh = Bh + (size_t)nt * KK48 * 4096;

    f32x4 acc[4][4];
    #pragma unroll
    for (int i = 0; i < 4; ++i)
        #pragma unroll
        for (int j2 = 0; j2 < 4; ++j2) acc[i][j2] = (f32x4){0.f, 0.f, 0.f, 0.f};

    float4 a0, a1, a2, a3;
    auto LOADA = [&](int kk) {
        float4 z = make_float4(0,0,0,0);
        a0 = a1 = a2 = a3 = z;
        if (r0v) { a0 = *(const float4*)(x0 + kk*32); a1 = *(const float4*)(x0 + kk*32 + 4); }
        if (r1v) { a2 = *(const float4*)(x1 + kk*32); a3 = *(const float4*)(x1 + kk*32 + 4); }
    };
    auto STAGEB = [&](int kk, int buf) {
        const size_t off = (size_t)kk * 4096 + wave * 1024 + lane * 8;
        _Float16* d = &T[buf][1][wave * 1024];
        gl2lds16(Brh + off,       d);
        gl2lds16(Brh + off + 512, d + 512);
    };
    auto WRITEA = [&](int buf) {
        *(half8_t*)&T[buf][0][(size_t)i0 * 8]       = hi8(a0, a1);
        *(half8_t*)&T[buf][0][(size_t)(i0 + 1) * 8] = hi8(a2, a3);
    };

    // prologue
    LOADA(0); STAGEB(0, 0);
    asm volatile("s_waitcnt vmcnt(0)" ::: "memory");
    WRITEA(0);
    asm volatile("s_waitcnt lgkmcnt(0)" ::: "memory");
    __builtin_amdgcn_s_barrier();

    int cur = 0;
    for (int kk = 0; kk < KK48; ++kk) {
        __builtin_amdgcn_sched_barrier(0);
        const bool more = (kk + 1 < KK48);
        if (more) { LOADA(kk + 1); STAGEB(kk + 1, cur ^ 1); }
        __builtin_amdgcn_sched_barrier(0);

        half8_t ah[4], bh[4];
        const half8_t* tA = (const half8_t*)&T[cur][0][0];
        const half8_t* tB = (const half8_t*)&T[cur][1][0];
        #pragma unroll
        for (int ms = 0; ms < 4; ++ms) ah[ms] = tA[((wm >> 4) + ms) * 64 + lane];
        #pragma unroll
        for (int ns = 0; ns < 4; ++ns) bh[ns] = tB[((wn >> 4) + ns) * 64 + lane];

        __builtin_amdgcn_s_setprio(1);
        #pragma unroll
        for (int ms = 0; ms < 4; ++ms)
            #pragma unroll
            for (int ns = 0; ns < 4; ++ns)
                acc[ms][ns] = __builtin_amdgcn_mfma_f32_16x16x32_f16(ah[ms], bh[ns], acc[ms][ns], 0, 0, 0);
        __builtin_amdgcn_s_setprio(0);

        if (more) {
            asm volatile("s_waitcnt vmcnt(0)" ::: "memory");
            WRITEA(cur ^ 1);
        }
        asm volatile("s_waitcnt lgkmcnt(0)" ::: "memory");
        __builtin_amdgcn_sched_barrier(0);
        __builtin_amdgcn_s_barrier();
        cur ^= 1;
    }

    float bv[4];
    #pragma unroll
    for (int ns = 0; ns < 4; ++ns) bv[ns] = bias[n0 + wn + ns*16 + l16];
    #pragma unroll
    for (int ms = 0; ms < 4; ++ms)
        #pragma unroll
        for (int r = 0; r < 4; ++r) {
            const int row = m0 + wm + ms*16 + quad*4 + r;
            if (row < M) {
                #pragma unroll
                for (int ns = 0; ns < 4; ++ns)
                    C[(size_t)row * DIM + n0 + wn + ns*16 + l16] = acc[ms][ns][r] + bv[ns];
            }
        }
}

// ---------------- 3-pass hi/lo fp16 GEMM (v), direct f32-A staging ----------
__global__ __launch_bounds__(256) void gemm_fl_d(
    const float* __restrict__ X,
    const _Float16* __restrict__ Bh, const _Float16* __restrict__ Bl,
    const float* __restrict__ bias,
    float* __restrict__ C, int M)
{
    __shared__ __align__(16) _Float16 T[2][4][4096];   // Ah, Al, Bh, Bl

    const int nwg = gridDim.x;               // 12*MT
    const int L = blockIdx.x;
    const int q8 = nwg >> 3, r8 = nwg & 7;
    const int xcd = L & 7, si = L >> 3;
    const int logical = (xcd < r8 ? xcd * (q8 + 1)
                                  : r8 * (q8 + 1) + (xcd - r8) * q8) + si;
    const int nt  = logical % 12;
    const int myy = logical / 12;
    const int m0 = myy * 128, n0 = nt * 128;

    const int tid = threadIdx.x;
    const int lane = tid & 63, wave = tid >> 6;
    const int l16 = lane & 15, quad = lane >> 4;
    const int wm = (wave >> 1) * 64, wn = (wave & 1) * 64;

    const int i0 = tid * 2;
    const int g0 = i0 >> 6,     lr0 = i0 & 63;
    const int g1 = (i0+1) >> 6, lr1 = (i0+1) & 63;
    const int row0 = m0 + g0 * 16 + (lr0 & 15);
    const int row1 = m0 + g1 * 16 + (lr1 & 15);
    const bool r0v = row0 < M, r1v = row1 < M;
    const float* x0 = X + (size_t)(r0v ? row0 : 0) * DIM + (lr0 >> 4) * 8;
    const float* x1 = X + (size_t)(r1v ? row1 : 0) * DIM + (lr1 >> 4) * 8;

    const _Float16* Brh = Bh + (size_t)nt * KK48 * 4096;
    const _Float16* Brl = Bl + (size_t)nt * KK48 * 4096;

    f32x4 acc[4][4];
    #pragma unroll
    for (int i = 0; i < 4; ++i)
        #pragma unroll
        for (int j2 = 0; j2 < 4; ++j2) acc[i][j2] = (f32x4){0.f, 0.f, 0.f, 0.f};

    float4 a0, a1, a2, a3;
    auto LOADA = [&](int kk) {
        float4 z = make_float4(0,0,0,0);
        a0 = a1 = a2 = a3 = z;
        if (r0v) { a0 = *(const float4*)(x0 + kk*32); a1 = *(const float4*)(x0 + kk*32 + 4); }
        if (r1v) { a2 = *(const float4*)(x1 + kk*32); a3 = *(const float4*)(x1 + kk*32 + 4); }
    };
    auto STAGEB = [&](int kk, int buf) {
        const size_t off = (size_t)kk * 4096 + wave * 1024 + lane * 8;
        _Float16* d2 = &T[buf][2][wave * 1024];
        _Float16* d3 = &T[buf][3][wave * 1024];
        gl2lds16(Brh + off,       d2);
        gl2lds16(Brh + off + 512, d2 + 512);
        gl2lds16(Brl + off,       d3);
        gl2lds16(Brl + off + 512, d3 + 512);
    };
    auto WRITEA = [&](int buf) {
        half8_t h, l;
        split8(a0, a1, h, l);
        *(half8_t*)&T[buf][0][(size_t)i0 * 8] = h;
        *(half8_t*)&T[buf][1][(size_t)i0 * 8] = l;
        split8(a2, a3, h, l);
        *(half8_t*)&T[buf][0][(size_t)(i0 + 1) * 8] = h;
        *(half8_t*)&T[buf][1][(size_t)(i0 + 1) * 8] = l;
    };

    LOADA(0); STAGEB(0, 0);
    asm volatile("s_waitcnt vmcnt(0)" ::: "memory");
    WRITEA(0);
    asm volatile("s_waitcnt lgkmcnt(0)" ::: "memory");
    __builtin_amdgcn_s_barrier();

    int cur = 0;
    for (int kk = 0; kk < KK48; ++kk) {
        __builtin_amdgcn_sched_barrier(0);
        const bool more = (kk + 1 < KK48);
        if (more) { LOADA(kk + 1); STAGEB(kk + 1, cur ^ 1); }
        __builtin_amdgcn_sched_barrier(0);

        half8_t ah[4], al[4], bh[4], bl[4];
        const half8_t* tA = (const half8_t*)&T[cur][0][0];
        const half8_t* tAl= (const half8_t*)&T[cur][1][0];
        const half8_t* tB = (const half8_t*)&T[cur][2][0];
        const half8_t* tBl= (const half8_t*)&T[cur][3][0];
        #pragma unroll
        for (int ms = 0; ms < 4; ++ms) {
            ah[ms] = tA [((wm >> 4) + ms) * 64 + lane];
            al[ms] = tAl[((wm >> 4) + ms) * 64 + lane];
        }
        #pragma unroll
        for (int ns = 0; ns < 4; ++ns) {
            bh[ns] = tB [((wn >> 4) + ns) * 64 + lane];
            bl[ns] = tBl[((wn >> 4) + ns) * 64 + lane];
        }
        __builtin_amdgcn_s_setprio(1);
        #pragma unroll
        for (int ms = 0; ms < 4; ++ms)
            #pragma unroll
            for (int ns = 0; ns < 4; ++ns) {
                acc[ms][ns] = __builtin_amdgcn_mfma_f32_16x16x32_f16(ah[ms], bh[ns], acc[ms][ns], 0, 0, 0);
                acc[ms][ns] = __builtin_amdgcn_mfma_f32_16x16x32_f16(ah[ms], bl[ns], acc[ms][ns], 0, 0, 0);
                acc[ms][ns] = __builtin_amdgcn_mfma_f32_16x16x32_f16(al[ms], bh[ns], acc[ms][ns], 0, 0, 0);
            }
        __builtin_amdgcn_s_setprio(0);

        if (more) {
            asm volatile("s_waitcnt vmcnt(0)" ::: "memory");
            WRITEA(cur ^ 1);
        }
        asm volatile("s_waitcnt lgkmcnt(0)" ::: "memory");
        __builtin_amdgcn_sched_barrier(0);
        __builtin_amdgcn_s_barrier();
        cur ^= 1;
    }

    float bv[4];
    #pragma unroll
    for (int ns = 0; ns < 4; ++ns) bv[ns] = bias[n0 + wn + ns*16 + l16];
    #pragma unroll
    for (int ms = 0; ms < 4; ++ms)
        #pragma unroll
        for (int r = 0; r < 4; ++r) {
            const int row = m0 + wm + ms*16 + quad*4 + r;
            if (row < M) {
                #pragma unroll
                for (int ns = 0; ns < 4; ++ns)
                    C[(size_t)row * DIM + n0 + wn + ns*16 + l16] = acc[ms][ns][r] + bv[ns];
            }
        }
}

// ---------------- 3-pass hi/lo fp16 GEMM on records (out-projection) -------
__global__ __launch_bounds__(256) void gemm_fl(
    const _Float16* __restrict__ Ah, const _Float16* __restrict__ Al,
    const _Float16* __restrict__ Bh, const _Float16* __restrict__ Bl,
    const float* __restrict__ bias,
    float* __restrict__ C, int M)
{
    __shared__ __align__(16) _Float16 T[2][4][4096];

    const int nwg = gridDim.x;               // 12*MT
    const int L = blockIdx.x;
    const int q8 = nwg >> 3, r8 = nwg & 7;
    const int xcd = L & 7, si = L >> 3;
    const int logical = (xcd < r8 ? xcd * (q8 + 1)
                                  : r8 * (q8 + 1) + (xcd - r8) * q8) + si;
    const int nt  = logical % 12;
    const int myy = logical / 12;
    const int m0 = myy * 128, n0 = nt * 128;

    const int tid = threadIdx.x;
    const int lane = tid & 63, wave = tid >> 6;
    const int l16 = lane & 15, quad = lane >> 4;
    const int wm = (wave >> 1) * 64, wn = (wave & 1) * 64;

    const _Float16* Arh = Ah + (size_t)myy * KK48 * 4096;
    const _Float16* Arl = Al + (size_t)myy * KK48 * 4096;
    const _Float16* Brh = Bh + (size_t)nt  * KK48 * 4096;
    const _Float16* Brl = Bl + (size_t)nt  * KK48 * 4096;

    f32x4 acc[4][4];
    #pragma unroll
    for (int i = 0; i < 4; ++i)
        #pragma unroll
        for (int j2 = 0; j2 < 4; ++j2) acc[i][j2] = (f32x4){0.f, 0.f, 0.f, 0.f};

    auto STAGE = [&](int kk, int buf) {
        const size_t off = (size_t)kk * 4096 + wave * 1024 + lane * 8;
        _Float16* d0 = &T[buf][0][wave * 1024];
        _Float16* d1 = &T[buf][1][wave * 1024];
        _Float16* d2 = &T[buf][2][wave * 1024];
        _Float16* d3 = &T[buf][3][wave * 1024];
        gl2lds16(Arh + off,       d0);
        gl2lds16(Arh + off + 512, d0 + 512);
        gl2lds16(Arl + off,       d1);
        gl2lds16(Arl + off + 512, d1 + 512);
        gl2lds16(Brh + off,       d2);
        gl2lds16(Brh + off + 512, d2 + 512);
        gl2lds16(Brl + off,       d3);
        gl2lds16(Brl + off + 512, d3 + 512);
    };

    STAGE(0, 0);
    int cur = 0;
    for (int kk = 0; kk < KK48; ++kk) {
        if (kk + 1 < KK48) {
            STAGE(kk + 1, cur ^ 1);
            asm volatile("s_waitcnt vmcnt(8)" ::: "memory");
        } else {
            asm volatile("s_waitcnt vmcnt(0)" ::: "memory");
        }
        __builtin_amdgcn_s_barrier();
        __builtin_amdgcn_sched_barrier(0);

        half8_t ah[4], al[4], bh[4], bl[4];
        const half8_t* tA = (const half8_t*)&T[cur][0][0];
        const half8_t* tAl= (const half8_t*)&T[cur][1][0];
        const half8_t* tB = (const half8_t*)&T[cur][2][0];
        const half8_t* tBl= (const half8_t*)&T[cur][3][0];
        #pragma unroll
        for (int ms = 0; ms < 4; ++ms) {
            ah[ms] = tA [((wm >> 4) + ms) * 64 + lane];
            al[ms] = tAl[((wm >> 4) + ms) * 64 + lane];
        }
        #pragma unroll
        for (int ns = 0; ns < 4; ++ns) {
            bh[ns] = tB [((wn >> 4) + ns) * 64 + lane];
            bl[ns] = tBl[((wn >> 4) + ns) * 64 + lane];
        }
        __builtin_amdgcn_s_setprio(1);
        #pragma unroll
        for (int ms = 0; ms < 4; ++ms)
            #pragma unroll
            for (int ns = 0; ns < 4; ++ns) {
                acc[ms][ns] = __builtin_amdgcn_mfma_f32_16x16x32_f16(ah[ms], bh[ns], acc[ms][ns], 0, 0, 0);
                acc[ms][ns] = __builtin_amdgcn_mfma_f32_16x16x32_f16(ah[ms], bl[ns], acc[ms][ns], 0, 0, 0);
                acc[ms][ns] = __builtin_amdgcn_mfma_f32_16x16x32_f16(al[ms], bh[ns], acc[ms][ns], 0, 0, 0);
            }
        __builtin_amdgcn_s_setprio(0);

        __builtin_amdgcn_sched_barrier(0);
        __builtin_amdgcn_s_barrier();
        cur ^= 1;
    }

    float bv[4];
    #pragma unroll
    for (int ns = 0; ns < 4; ++ns) bv[ns] = bias[n0 + wn + ns*16 + l16];
    #pragma unroll
    for (int ms = 0; ms < 4; ++ms)
        #pragma unroll
        for (int r = 0; r < 4; ++r) {
            const int row = m0 + wm + ms*16 + quad*4 + r;
            if (row < M) {
                #pragma unroll
                for (int ns = 0; ns < 4; ++ns)
                    C[(size_t)row * DIM + n0 + wn + ns*16 + l16] = acc[ms][ns][r] + bv[ns];
            }
        }
}

// ---------------- RMSNorm + 3D RoPE for q and k in one launch ----------------
__global__ __launch_bounds__(256) void rms_rope2(
    float* __restrict__ qb, float* __restrict__ kb,
    const float* __restrict__ wq_, const float* __restrict__ wk_,
    const float* __restrict__ freqs,
    const int* __restrict__ fp, const int* __restrict__ hp,
    const int* __restrict__ wp, const int* __restrict__ gip)
{
    const int s = blockIdx.x;
    float* xv = blockIdx.y ? kb : qb;
    const float* w = blockIdx.y ? wk_ : wq_;
    const int tid = threadIdx.x;
    float* row = xv + (size_t)s * DIM;
    float ss = 0.f;
    for (int c = tid; c < DIM; c += 256) { float v = row[c]; ss += v * v; }
    #pragma unroll
    for (int off = 32; off > 0; off >>= 1) ss += __shfl_down(ss, off, 64);
    __shared__ float red[4];
    if ((tid & 63) == 0) red[tid >> 6] = ss;
    __syncthreads();
    const float tot = red[0] + red[1] + red[2] + red[3];
    const float scale = rsqrtf(tot / (float)DIM + 1e-6f);
    const int f = *fp, h = *hp, ww = *wp, gi = *gip;
    const int hw = h * ww;
    const int fi = s / hw;
    const int rem = s - fi * hw;
    const int hi = rem / ww;
    const int wi = rem - hi * ww;
    const int sf = gi * f;
    for (int p = tid; p < DIM / 2; p += 256) {
        int n = p >> 6, i = p & 63;
        int pos = (i < 22) ? (sf + fi) : (i < 43) ? hi : wi;
        float cs = freqs[pos * 128 + i * 2];
        float sn = freqs[pos * 128 + i * 2 + 1];
        int base = n * HD + 2 * i;
        float x0 = row[base] * scale * w[base];
        float x1 = row[base + 1] * scale * w[base + 1];
        row[base] = x0 * cs - x1 * sn;
        row[base + 1] = x0 * sn + x1 * cs;
    }
}

// ---------------- K+V prep: single-f16 RN, frag-linear KV records ----------
// V k-slots PERMUTED: slot s holds key (s>>1) + 16*(s&1), matching the
// interleaved packed-P layout. V reads now vectorized: one key row per 8
// threads, 4x float4 (was 8 scalar strided loads/thread); same RN convert.
__global__ __launch_bounds__(256) void kv_prep(
    const float* __restrict__ kws, const float* __restrict__ kcache,
    const float* __restrict__ vws, const float* __restrict__ vcache,
    _Float16* __restrict__ KV, int S, int NT, const int* __restrict__ gip)
{
    const int t = blockIdx.x, n = blockIdx.y;
    const int tid = threadIdx.x;
    const int lane = tid & 63;
    const int l16 = lane & 15, quad = lane >> 4;
    const int start = gip[0] * S;
    const int nk = start + S;
    _Float16* outk = KV + (size_t)(n * NT + t) * 8192;
    _Float16* outv = outk + 4096;
    // K part: frag-linear, pkrtz-free RN convert (unchanged)
    #pragma unroll
    for (int fi = 0; fi < 2; ++fi) {
        const int f = (tid >> 6) + fi * 4;
        const int ks = f >> 2, db = f & 3;
        const int j = t * KT + ks * 16 + l16;
        float4 a = make_float4(0,0,0,0), b = a;
        if (j < nk) {
            const float* src = (j < start) ? (kcache + (size_t)j * DIM)
                                           : (kws + (size_t)(j - start) * DIM);
            src += n * HD + db * 32 + quad * 8;
            a = *(const float4*)src;
            b = *(const float4*)(src + 4);
        }
        *(half8_t*)&outk[(f * 64 + lane) * 8] = cvt8rn(a, b);
    }
    // V part: row r = tid>>3, dims c0..c0+15, slot s with perm(s) = r
    {
        const int r  = tid >> 3;             // 0..31
        const int c0 = (tid & 7) * 16;       // 0..112
        const int key = t * KT + r;
        const int s  = (r & 15) * 2 + (r >> 4);
        float4 va = make_float4(0,0,0,0), vb = va, vc = va, vd = va;
        if (key < nk) {
            const float* src = (key < start) ? (vcache + (size_t)key * DIM)
                                             : (vws + (size_t)(key - start) * DIM);
            src += n * HD + c0;
            va = ((const float4*)src)[0];
            vb = ((const float4*)src)[1];
            vc = ((const float4*)src)[2];
            vd = ((const float4*)src)[3];
        }
        _Float16* o = outv + ((size_t)((c0 >> 4) * 64 + (s >> 3) * 16) * 8) + (s & 7);
        o[0]   = (_Float16)va.x; o[8]   = (_Float16)va.y;
        o[16]  = (_Float16)va.z; o[24]  = (_Float16)va.w;
        o[32]  = (_Float16)vb.x; o[40]  = (_Float16)vb.y;
        o[48]  = (_Float16)vb.z; o[56]  = (_Float16)vb.w;
        o[64]  = (_Float16)vc.x; o[72]  = (_Float16)vc.y;
        o[80]  = (_Float16)vc.z; o[88]  = (_Float16)vc.w;
        o[96]  = (_Float16)vd.x; o[104] = (_Float16)vd.y;
        o[112] = (_Float16)vd.z; o[120] = (_Float16)vd.w;
    }
}

// ---------------- MFMA flash attention (round-8, unchanged) ----------------
#define PSTRH 36
__global__ __launch_bounds__(256, 3) void attn_mfma(
    const float* __restrict__ q,
    const _Float16* __restrict__ KV,
    float* __restrict__ Op, float* __restrict__ Ml,
    int S, int NT, const int* __restrict__ gip)
{
    __shared__ __align__(16) _Float16 T[2][8192];   // [K 4096 | Vt 4096]
    __shared__ __align__(16) _Float16 Ph[4][2][16][PSTRH];

    const int nwg = gridDim.x;
    const int L = blockIdx.x;
    const int q8 = nwg >> 3, r8 = nwg & 7;
    const int xcd = L & 7, si = L >> 3;
    const int logical = (xcd < r8 ? xcd * (q8 + 1)
                                  : r8 * (q8 + 1) + (xcd - r8) * q8) + si;
    const int yb = (S + 127) >> 7;
    const int y = logical % yb;
    const int g = logical / yb;
    const int n = g % NH;
    const int ksp = g / NH;
    const int q0 = y * 128;

    const int tid = threadIdx.x;
    const int wave = tid >> 6;          // 0..3
    const int lane = tid & 63;
    const int l16 = lane & 15;
    const int quad = lane >> 4;
    const int start = gip[0] * S;
    const int nk = start + S;
    const int totTiles = (nk + KT - 1) / KT;
    const int tilesPer = (totTiles + KSPLIT - 1) / KSPLIT;
    const int t0 = ksp * tilesPer;
    const int t1 = min(t0 + tilesPer, totTiles);
    const float sc = 0.08838834764831845f;

    half8_t qf[2][4];
    #pragma unroll
    for (int qs = 0; qs < 2; ++qs) {
        const int qrow = q0 + wave * 32 + qs * 16 + l16;
        const bool qv = qrow < S;
        const float* qp = q + (size_t)(qv ? qrow : 0) * DIM + n * HD + quad * 8;
        #pragma unroll
        for (int db = 0; db < 4; ++db) {
            float4 a = make_float4(0,0,0,0), b = a;
            if (qv) { a = *(const float4*)(qp + db * 32); b = *(const float4*)(qp + db * 32 + 4); }
            qf[qs][db] = cvt8rn(a, b);
        }
    }

    half8_t ones_f;
    {
        _Float16 ov = (l16 == 0) ? (_Float16)1.0f : (_Float16)0.0f;
        #pragma unroll
        for (int j = 0; j < 8; ++j) ones_f[j] = ov;
    }

    f32x4 O[2][9];
    #pragma unroll
    for (int qs = 0; qs < 2; ++qs)
        #pragma unroll
        for (int ds = 0; ds < 9; ++ds) O[qs][ds] = (f32x4){0.f, 0.f, 0.f, 0.f};

    const size_t tb = (size_t)n * NT;

    if (t0 < t1) {
        const _Float16* gp = KV + (tb + t0) * 8192 + wave * 1024 + lane * 8;
        _Float16* d = &T[0][wave * 1024];
        gl2lds16(gp,              d);
        gl2lds16(gp + 512,        d + 512);
        gl2lds16(gp + 4096,       d + 4096);
        gl2lds16(gp + 4096 + 512, d + 4096 + 512);
    }

    int cur = 0;
    for (int t = t0; t < t1; ++t) {
        if (t + 1 < t1) {
            const _Float16* gp = KV + (tb + t + 1) * 8192 + wave * 1024 + lane * 8;
            _Float16* d = &T[cur ^ 1][wave * 1024];
            gl2lds16(gp,              d);
            gl2lds16(gp + 512,        d + 512);
            gl2lds16(gp + 4096,       d + 4096);
            gl2lds16(gp + 4096 + 512, d + 4096 + 512);
            asm volatile("s_waitcnt vmcnt(4)" ::: "memory");
        } else {
            asm volatile("s_waitcnt vmcnt(0)" ::: "memory");
        }
        __builtin_amdgcn_s_barrier();
        __builtin_amdgcn_sched_barrier(0);

        f32x4 sacc[2][2];
        #pragma unroll
        for (int qs = 0; qs < 2; ++qs) {
            sacc[qs][0] = (f32x4){0.f, 0.f, 0.f, 0.f};
            sacc[qs][1] = (f32x4){0.f, 0.f, 0.f, 0.f};
        }
        const half8_t* kh8 = (const half8_t*)&T[cur][0];
        __builtin_amdgcn_s_setprio(1);
        #pragma unroll
        for (int ks = 0; ks < 2; ++ks) {
            #pragma unroll
            for (int db = 0; db < 4; ++db) {
                half8_t bh = kh8[(ks * 4 + db) * 64 + lane];
                sacc[0][ks] = __builtin_amdgcn_mfma_f32_16x16x32_f16(qf[0][db], bh, sacc[0][ks], 0, 0, 0);
                sacc[1][ks] = __builtin_amdgcn_mfma_f32_16x16x32_f16(qf[1][db], bh, sacc[1][ks], 0, 0, 0);
            }
        }
        __builtin_amdgcn_s_setprio(0);

        const int k0 = t * KT;
        const bool v0 = (k0 + l16) < nk;
        const bool v1 = (k0 + 16 + l16) < nk;
        #pragma unroll
        for (int qs = 0; qs < 2; ++qs) {
            #pragma unroll
            for (int r = 0; r < 4; ++r) {
                float p0 = v0 ? __expf(sacc[qs][0][r] * sc - MFIX) : 0.f;
                float p1 = v1 ? __expf(sacc[qs][1][r] * sc - MFIX) : 0.f;
                half2_t pp;
                pp.x = (_Float16)p0;
                pp.y = (_Float16)p1;
                *(half2_t*)&Ph[wave][qs][quad * 4 + r][2 * l16] = pp;
            }
        }

        half8_t ph[2];
        #pragma unroll
        for (int qs = 0; qs < 2; ++qs)
            ph[qs] = *(const half8_t*)&Ph[wave][qs][l16][quad * 8];

        const half8_t* vt8 = (const half8_t*)&T[cur][4096];
        __builtin_amdgcn_s_setprio(1);
        #pragma unroll
        for (int ds = 0; ds < 8; ++ds) {
            half8_t vh = vt8[ds * 64 + lane];
            O[0][ds] = __builtin_amdgcn_mfma_f32_16x16x32_f16(ph[0], vh, O[0][ds], 0, 0, 0);
            O[1][ds] = __builtin_amdgcn_mfma_f32_16x16x32_f16(ph[1], vh, O[1][ds], 0, 0, 0);
        }
        O[0][8] = __builtin_amdgcn_mfma_f32_16x16x32_f16(ph[0], ones_f, O[0][8], 0, 0, 0);
        O[1][8] = __builtin_amdgcn_mfma_f32_16x16x32_f16(ph[1], ones_f, O[1][8], 0, 0, 0);
        __builtin_amdgcn_s_setprio(0);

        __builtin_amdgcn_sched_barrier(0);
        __builtin_amdgcn_s_barrier();
        cur ^= 1;
    }

    #pragma unroll
    for (int qs = 0; qs < 2; ++qs)
        #pragma unroll
        for (int r = 0; r < 4; ++r) {
            const int row = q0 + wave * 32 + qs * 16 + quad * 4 + r;
            if (row < S) {
                float* op = Op + (((size_t)ksp * NH + n) * S + row) * HD + l16;
                #pragma unroll
                for (int ds = 0; ds < 8; ++ds) op[ds * 16] = O[qs][ds][r];
                if (l16 == 0)
                    Ml[((size_t)ksp * NH + n) * S + row] = O[qs][8][r];
            }
        }
}

// ------- merge split-K partials -> frag-linear hi/lo A-records for out-GEMM -------
__global__ __launch_bounds__(256) void attn_merge(
    const float* __restrict__ Op, const float* __restrict__ Ml,
    _Float16* __restrict__ oh, _Float16* __restrict__ ol, int S)
{
    const int idx = blockIdx.x * 256 + threadIdx.x;
    const int total = NH * S * HD / 2;
    if (idx >= total) return;
    const int d0 = (idx & 63) * 2;
    const int t = idx >> 6;
    const int row = t % S;
    const int n = t / S;
    float num0 = 0.f, num1 = 0.f, den = 0.f;
    #pragma unroll
    for (int ks = 0; ks < KSPLIT; ++ks) {
        const size_t base = ((size_t)ks * NH + n) * S + row;
        num0 += Op[base * HD + d0];
        num1 += Op[base * HD + d0 + 1];
        den += Ml[base];
    }
    const float v0 = num0 / den, v1 = num1 / den;
    half2_t h = pkrtz(v0, v1);
    half2_t l = pkrtz(v0 - (float)h.x, v1 - (float)h.y);
    const int k = n * HD + d0;
    const int mt = row >> 7, rr = row & 127;
    const int grp = rr >> 4, l16r = rr & 15;
    const int kk = k >> 5, quad = (k & 31) >> 3, jj = k & 7;
    const size_t a = ((size_t)(mt * KK48 + kk) * 4096)
                   + ((size_t)(grp * 64 + quad * 16 + l16r) * 8) + jj;
    *(half2_t*)&oh[a] = h;
    *(half2_t*)&ol[a] = l;
}

extern "C" void kernel_launch(void* const* d_in, const int* in_sizes, int n_in,
                              void* d_out, int out_size, void* d_ws, size_t ws_size,
                              hipStream_t stream)
{
    const float* x      = (const float*)d_in[0];
    const float* wq     = (const float*)d_in[1];
    const float* bq     = (const float*)d_in[2];
    const float* wk     = (const float*)d_in[3];
    const float* bk     = (const float*)d_in[4];
    const float* wv     = (const float*)d_in[5];
    const float* bv     = (const float*)d_in[6];
    const float* wo     = (const float*)d_in[7];
    const float* bo     = (const float*)d_in[8];
    const float* nqw    = (const float*)d_in[9];
    const float* nkw    = (const float*)d_in[10];
    const float* freqs  = (const float*)d_in[11];
    const float* kcache = (const float*)d_in[12];
    const float* vcache = (const float*)d_in[13];
    const int*   fp     = (const int*)d_in[14];
    const int*   hp     = (const int*)d_in[15];
    const int*   wp     = (const int*)d_in[16];
    const int*   gip    = (const int*)d_in[17];

    const int S = in_sizes[0] / DIM;
    const int total = in_sizes[12] / (NH * HD);
    const int NT = (total + KT - 1) / KT;
    const int MT = (S + 127) / 128;
    const size_t sd = (size_t)S * DIM;
    const size_t arec = (size_t)MT * KK48 * 4096;   // halfs per A-record buffer
    const size_t wrec = (size_t)12 * KK48 * 4096;   // halfs per W-record buffer

    char* p = (char*)d_ws;
    float* q  = (float*)p;            p += sd * 4;
    float* k  = (float*)p;            p += sd * 4;
    float* v  = (float*)p;            p += sd * 4;
    float* Op = (float*)p;            p += (size_t)KSPLIT * NH * S * HD * 4;
    float* Ml = (float*)p;            p += (size_t)KSPLIT * NH * S * 4;
    _Float16* KV  = (_Float16*)p;     p += (size_t)NH * NT * 8192 * 2;
    _Float16* oh  = (_Float16*)p;     p += arec * 2;
    _Float16* ol  = (_Float16*)p;     p += arec * 2;
    _Float16* wqh = (_Float16*)p;     p += wrec * 2;
    _Float16* wql = (_Float16*)p;     p += wrec * 2;
    _Float16* wkh = (_Float16*)p;     p += wrec * 2;
    _Float16* wkl = (_Float16*)p;     p += wrec * 2;
    _Float16* wvh = (_Float16*)p;     p += wrec * 2;
    _Float16* wvl = (_Float16*)p;     p += wrec * 2;
    _Float16* woh = (_Float16*)p;     p += wrec * 2;
    _Float16* wol = (_Float16*)p;     p += wrec * 2;
    float* out = (float*)d_out;

    const int wn8 = (int)(wrec / 8);

    cvt_w_fl<<<dim3((wn8 + 255) / 256, 4), dim3(256), 0, stream>>>(
        wq, wk, wv, wo, wqh, wql, wkh, wkl, wvh, wvl, woh, wol, wn8);

    // q,k: single-pass, direct f32-A staging (cvt_a eliminated)
    gemm_fl_s<<<dim3(24 * MT), dim3(256), 0, stream>>>(
        x, wqh, wkh, bq, bk, q, k, S);
    // v: full hi/lo 3-pass, direct f32-A staging
    gemm_fl_d<<<dim3(12 * MT), dim3(256), 0, stream>>>(
        x, wvh, wvl, bv, v, S);
    rms_rope2<<<dim3(S, 2), dim3(256), 0, stream>>>(q, k, nqw, nkw, freqs, fp, hp, wp, gip);
    kv_prep<<<dim3(NT, NH), dim3(256), 0, stream>>>(k, kcache, v, vcache, KV, S, NT, gip);
    {
        const int yb = (S + 127) / 128;
        const int nwg = NH * yb * KSPLIT;
        attn_mfma<<<dim3(nwg), dim3(256), 0, stream>>>(
            q, KV, Op, Ml, S, NT, gip);
    }
    attn_merge<<<dim3((NH * S * HD / 2 + 255) / 256), dim3(256), 0, stream>>>(Op, Ml, oh, ol, S);
    gemm_fl<<<dim3(12 * MT), dim3(256), 0, stream>>>(
        oh, ol, woh, wol, bo, out, S);
}

// Round 13
// 454.244 us; speedup vs baseline: 1.1167x; 1.1167x over previous
//
#include <hip/hip_runtime.h>

#define DIM 1536
#define NH 12
#define HD 128
#define KSPLIT 8
#define KT 32
#define MFIX 3.0f
#define KK48 48   // DIM/32 K-steps

typedef _Float16 half2_t __attribute__((ext_vector_type(2)));
typedef _Float16 half8_t __attribute__((ext_vector_type(8)));
typedef float f32x4 __attribute__((ext_vector_type(4)));

__device__ __forceinline__ half2_t pkrtz(float a, float b) {
    return __builtin_bit_cast(half2_t, __builtin_amdgcn_cvt_pkrtz(a, b));
}

__device__ __forceinline__ void split8(float4 a, float4 b, half8_t& h, half8_t& l) {
    half2_t h0 = pkrtz(a.x, a.y), h1 = pkrtz(a.z, a.w);
    half2_t h2 = pkrtz(b.x, b.y), h3 = pkrtz(b.z, b.w);
    half2_t g0 = pkrtz(a.x - (float)h0.x, a.y - (float)h0.y);
    half2_t g1 = pkrtz(a.z - (float)h1.x, a.w - (float)h1.y);
    half2_t g2 = pkrtz(b.x - (float)h2.x, b.y - (float)h2.y);
    half2_t g3 = pkrtz(b.z - (float)h3.x, b.w - (float)h3.y);
    h[0]=h0.x; h[1]=h0.y; h[2]=h1.x; h[3]=h1.y; h[4]=h2.x; h[5]=h2.y; h[6]=h3.x; h[7]=h3.y;
    l[0]=g0.x; l[1]=g0.y; l[2]=g1.x; l[3]=g1.y; l[4]=g2.x; l[5]=g2.y; l[6]=g3.x; l[7]=g3.y;
}

// round-to-nearest f32x8 -> f16x8 (attention Q/K/V single-precision path)
__device__ __forceinline__ half8_t cvt8rn(float4 a, float4 b) {
    half8_t h;
    h[0]=(_Float16)a.x; h[1]=(_Float16)a.y; h[2]=(_Float16)a.z; h[3]=(_Float16)a.w;
    h[4]=(_Float16)b.x; h[5]=(_Float16)b.y; h[6]=(_Float16)b.z; h[7]=(_Float16)b.w;
    return h;
}

// async global->LDS, 16 B per lane; lds must be wave-uniform, HW adds lane*16
__device__ __forceinline__ void gl2lds16(const void* g, void* l) {
    __builtin_amdgcn_global_load_lds(
        (const __attribute__((address_space(1))) unsigned int*)g,
        (__attribute__((address_space(3))) unsigned int*)(unsigned int)(uintptr_t)l,
        16, 0, 0);
}

// ===== MFMA-frag-linear tile records =====
// A 128x32 (rows x k) f16 tile stored as rec[grp(8)][lane(64)][j(8)]:
//   row = grp*16 + (lane&15), k = (lane>>4)*8 + j  (4096 halfs = 8 KB).

// ---------------- x -> frag-linear hi/lo A-records ----------------
__global__ __launch_bounds__(256) void cvt_a_fl(
    const float* __restrict__ src, _Float16* __restrict__ h, _Float16* __restrict__ l,
    int M, int nrec8)
{
    const int i = blockIdx.x * 256 + threadIdx.x;
    if (i >= nrec8) return;
    const int lane = i & 63;
    const int grp  = (i >> 6) & 7;
    const int tile = i >> 9;                  // mt*KK48 + kk
    const int kk = tile % KK48, mt = tile / KK48;
    const int row = mt * 128 + grp * 16 + (lane & 15);
    const int k   = kk * 32 + (lane >> 4) * 8;
    float4 a = make_float4(0,0,0,0), b = a;
    if (row < M) {
        const float* s = src + (size_t)row * DIM + k;
        a = *(const float4*)s; b = *(const float4*)(s + 4);
    }
    half8_t hh, ll; split8(a, b, hh, ll);
    ((half8_t*)h)[i] = hh;
    ((half8_t*)l)[i] = ll;
}

// ---------------- 4 weight matrices -> frag-linear hi/lo B-records ----------
// lo-halves only written for v (m=2) and wo (m=3): q,k run single-pass.
__global__ __launch_bounds__(256) void cvt_w_fl(
    const float* __restrict__ s0, const float* __restrict__ s1,
    const float* __restrict__ s2, const float* __restrict__ s3,
    _Float16* __restrict__ h0, _Float16* __restrict__ l0,
    _Float16* __restrict__ h1, _Float16* __restrict__ l1,
    _Float16* __restrict__ h2, _Float16* __restrict__ l2,
    _Float16* __restrict__ h3, _Float16* __restrict__ l3, int nrec8)
{
    const int i = blockIdx.x * 256 + threadIdx.x;
    if (i >= nrec8) return;
    const int m = blockIdx.y;
    const float* src = m == 0 ? s0 : m == 1 ? s1 : m == 2 ? s2 : s3;
    _Float16* h = m == 0 ? h0 : m == 1 ? h1 : m == 2 ? h2 : h3;
    _Float16* l = m == 0 ? l0 : m == 1 ? l1 : m == 2 ? l2 : l3;
    const int lane = i & 63;
    const int grp  = (i >> 6) & 7;
    const int tile = i >> 9;                  // nt*KK48 + kk
    const int kk = tile % KK48, nt = tile / KK48;
    const int row = nt * 128 + grp * 16 + (lane & 15);
    const int k   = kk * 32 + (lane >> 4) * 8;
    const float* s = src + (size_t)row * DIM + k;
    float4 a = *(const float4*)s, b = *(const float4*)(s + 4);
    half8_t hh, ll; split8(a, b, hh, ll);
    ((half8_t*)h)[i] = hh;
    if (m >= 2) ((half8_t*)l)[i] = ll;
}

// ---------------- single-pass fp16 GEMM (q,k): 32 KB LDS, 4 blocks/CU ------
__global__ __launch_bounds__(256, 4) void gemm_fl_s(
    const _Float16* __restrict__ Ah,
    const _Float16* __restrict__ Bh0, const _Float16* __restrict__ Bh1,
    const float* __restrict__ bias0, const float* __restrict__ bias1,
    float* __restrict__ C0, float* __restrict__ C1,
    int M)
{
    __shared__ __align__(16) _Float16 T[2][2][4096];   // Ah, Bh tiles

    const int nwg = gridDim.x;               // 24*MT
    const int L = blockIdx.x;
    const int q8 = nwg >> 3, r8 = nwg & 7;
    const int xcd = L & 7, si = L >> 3;
    const int logical = (xcd < r8 ? xcd * (q8 + 1)
                                  : r8 * (q8 + 1) + (xcd - r8) * q8) + si;
    const int j   = logical % 24;            // q/k interleaved, A-tile shared
    const int myy = logical / 24;
    const int mat = j & 1, nt = j >> 1;
    const _Float16* Bh   = mat ? Bh1 : Bh0;
    const float*    bias = mat ? bias1 : bias0;
    float*          C    = mat ? C1 : C0;
    const int m0 = myy * 128, n0 = nt * 128;

    const int tid = threadIdx.x;
    const int lane = tid & 63, wave = tid >> 6;
    const int l16 = lane & 15, quad = lane >> 4;
    const int wm = (wave >> 1) * 64, wn = (wave & 1) * 64;

    const _Float16* Arh = Ah + (size_t)myy * KK48 * 4096;
    const _Float16* Brh = Bh + (size_t)nt  * KK48 * 4096;

    f32x4 acc[4][4];
    #pragma unroll
    for (int i = 0; i < 4; ++i)
        #pragma unroll
        for (int j2 = 0; j2 < 4; ++j2) acc[i][j2] = (f32x4){0.f, 0.f, 0.f, 0.f};

    auto STAGE = [&](int kk, int buf) {
        const size_t off = (size_t)kk * 4096 + wave * 1024 + lane * 8;
        _Float16* d0 = &T[buf][0][wave * 1024];
        _Float16* d1 = &T[buf][1][wave * 1024];
        gl2lds16(Arh + off,       d0);
        gl2lds16(Arh + off + 512, d0 + 512);
        gl2lds16(Brh + off,       d1);
        gl2lds16(Brh + off + 512, d1 + 512);
    };

    STAGE(0, 0);
    int cur = 0;
    for (int kk = 0; kk < KK48; ++kk) {
        if (kk + 1 < KK48) {
            STAGE(kk + 1, cur ^ 1);
            asm volatile("s_waitcnt vmcnt(4)" ::: "memory");
        } else {
            asm volatile("s_waitcnt vmcnt(0)" ::: "memory");
        }
        __builtin_amdgcn_s_barrier();
        __builtin_amdgcn_sched_barrier(0);

        half8_t ah[4], bh[4];
        const half8_t* tA = (const half8_t*)&T[cur][0][0];
        const half8_t* tB = (const half8_t*)&T[cur][1][0];
        #pragma unroll
        for (int ms = 0; ms < 4; ++ms) ah[ms] = tA[((wm >> 4) + ms) * 64 + lane];
        #pragma unroll
        for (int ns = 0; ns < 4; ++ns) bh[ns] = tB[((wn >> 4) + ns) * 64 + lane];

        __builtin_amdgcn_s_setprio(1);
        #pragma unroll
        for (int ms = 0; ms < 4; ++ms)
            #pragma unroll
            for (int ns = 0; ns < 4; ++ns)
                acc[ms][ns] = __builtin_amdgcn_mfma_f32_16x16x32_f16(ah[ms], bh[ns], acc[ms][ns], 0, 0, 0);
        __builtin_amdgcn_s_setprio(0);

        __builtin_amdgcn_sched_barrier(0);
        __builtin_amdgcn_s_barrier();
        cur ^= 1;
    }

    float bv[4];
    #pragma unroll
    for (int ns = 0; ns < 4; ++ns) bv[ns] = bias[n0 + wn + ns*16 + l16];
    #pragma unroll
    for (int ms = 0; ms < 4; ++ms)
        #pragma unroll
        for (int r = 0; r < 4; ++r) {
            const int row = m0 + wm + ms*16 + quad*4 + r;
            if (row < M) {
                #pragma unroll
                for (int ns = 0; ns < 4; ++ns)
                    C[(size_t)row * DIM + n0 + wn + ns*16 + l16] = acc[ms][ns][r] + bv[ns];
            }
        }
}

// ---------------- 3-pass hi/lo fp16 GEMM, one weight matrix (v, out) -------
__global__ __launch_bounds__(256) void gemm_fl(
    const _Float16* __restrict__ Ah, const _Float16* __restrict__ Al,
    const _Float16* __restrict__ Bh, const _Float16* __restrict__ Bl,
    const float* __restrict__ bias,
    float* __restrict__ C, int M)
{
    __shared__ __align__(16) _Float16 T[2][4][4096];   // Ah, Al, Bh, Bl tiles

    const int nwg = gridDim.x;               // 12*MT
    const int L = blockIdx.x;
    const int q8 = nwg >> 3, r8 = nwg & 7;
    const int xcd = L & 7, si = L >> 3;
    const int logical = (xcd < r8 ? xcd * (q8 + 1)
                                  : r8 * (q8 + 1) + (xcd - r8) * q8) + si;
    const int nt  = logical % 12;
    const int myy = logical / 12;
    const int m0 = myy * 128, n0 = nt * 128;

    const int tid = threadIdx.x;
    const int lane = tid & 63, wave = tid >> 6;
    const int l16 = lane & 15, quad = lane >> 4;
    const int wm = (wave >> 1) * 64, wn = (wave & 1) * 64;

    const _Float16* Arh = Ah + (size_t)myy * KK48 * 4096;
    const _Float16* Arl = Al + (size_t)myy * KK48 * 4096;
    const _Float16* Brh = Bh + (size_t)nt  * KK48 * 4096;
    const _Float16* Brl = Bl + (size_t)nt  * KK48 * 4096;

    f32x4 acc[4][4];
    #pragma unroll
    for (int i = 0; i < 4; ++i)
        #pragma unroll
        for (int j2 = 0; j2 < 4; ++j2) acc[i][j2] = (f32x4){0.f, 0.f, 0.f, 0.f};

    auto STAGE = [&](int kk, int buf) {
        const size_t off = (size_t)kk * 4096 + wave * 1024 + lane * 8;
        _Float16* d0 = &T[buf][0][wave * 1024];
        _Float16* d1 = &T[buf][1][wave * 1024];
        _Float16* d2 = &T[buf][2][wave * 1024];
        _Float16* d3 = &T[buf][3][wave * 1024];
        gl2lds16(Arh + off,       d0);
        gl2lds16(Arh + off + 512, d0 + 512);
        gl2lds16(Arl + off,       d1);
        gl2lds16(Arl + off + 512, d1 + 512);
        gl2lds16(Brh + off,       d2);
        gl2lds16(Brh + off + 512, d2 + 512);
        gl2lds16(Brl + off,       d3);
        gl2lds16(Brl + off + 512, d3 + 512);
    };

    STAGE(0, 0);
    int cur = 0;
    for (int kk = 0; kk < KK48; ++kk) {
        if (kk + 1 < KK48) {
            STAGE(kk + 1, cur ^ 1);
            asm volatile("s_waitcnt vmcnt(8)" ::: "memory");
        } else {
            asm volatile("s_waitcnt vmcnt(0)" ::: "memory");
        }
        __builtin_amdgcn_s_barrier();
        __builtin_amdgcn_sched_barrier(0);

        half8_t ah[4], al[4], bh[4], bl[4];
        const half8_t* tA = (const half8_t*)&T[cur][0][0];
        const half8_t* tAl= (const half8_t*)&T[cur][1][0];
        const half8_t* tB = (const half8_t*)&T[cur][2][0];
        const half8_t* tBl= (const half8_t*)&T[cur][3][0];
        #pragma unroll
        for (int ms = 0; ms < 4; ++ms) {
            ah[ms] = tA [((wm >> 4) + ms) * 64 + lane];
            al[ms] = tAl[((wm >> 4) + ms) * 64 + lane];
        }
        #pragma unroll
        for (int ns = 0; ns < 4; ++ns) {
            bh[ns] = tB [((wn >> 4) + ns) * 64 + lane];
            bl[ns] = tBl[((wn >> 4) + ns) * 64 + lane];
        }
        __builtin_amdgcn_s_setprio(1);
        #pragma unroll
        for (int ms = 0; ms < 4; ++ms)
            #pragma unroll
            for (int ns = 0; ns < 4; ++ns) {
                acc[ms][ns] = __builtin_amdgcn_mfma_f32_16x16x32_f16(ah[ms], bh[ns], acc[ms][ns], 0, 0, 0);
                acc[ms][ns] = __builtin_amdgcn_mfma_f32_16x16x32_f16(ah[ms], bl[ns], acc[ms][ns], 0, 0, 0);
                acc[ms][ns] = __builtin_amdgcn_mfma_f32_16x16x32_f16(al[ms], bh[ns], acc[ms][ns], 0, 0, 0);
            }
        __builtin_amdgcn_s_setprio(0);

        __builtin_amdgcn_sched_barrier(0);
        __builtin_amdgcn_s_barrier();
        cur ^= 1;
    }

    float bv[4];
    #pragma unroll
    for (int ns = 0; ns < 4; ++ns) bv[ns] = bias[n0 + wn + ns*16 + l16];
    #pragma unroll
    for (int ms = 0; ms < 4; ++ms)
        #pragma unroll
        for (int r = 0; r < 4; ++r) {
            const int row = m0 + wm + ms*16 + quad*4 + r;
            if (row < M) {
                #pragma unroll
                for (int ns = 0; ns < 4; ++ns)
                    C[(size_t)row * DIM + n0 + wn + ns*16 + l16] = acc[ms][ns][r] + bv[ns];
            }
        }
}

// ---------------- RMSNorm + 3D RoPE for q and k in one launch ----------------
__global__ __launch_bounds__(256) void rms_rope2(
    float* __restrict__ qb, float* __restrict__ kb,
    const float* __restrict__ wq_, const float* __restrict__ wk_,
    const float* __restrict__ freqs,
    const int* __restrict__ fp, const int* __restrict__ hp,
    const int* __restrict__ wp, const int* __restrict__ gip)
{
    const int s = blockIdx.x;
    float* xv = blockIdx.y ? kb : qb;
    const float* w = blockIdx.y ? wk_ : wq_;
    const int tid = threadIdx.x;
    float* row = xv + (size_t)s * DIM;
    float ss = 0.f;
    for (int c = tid; c < DIM; c += 256) { float v = row[c]; ss += v * v; }
    #pragma unroll
    for (int off = 32; off > 0; off >>= 1) ss += __shfl_down(ss, off, 64);
    __shared__ float red[4];
    if ((tid & 63) == 0) red[tid >> 6] = ss;
    __syncthreads();
    const float tot = red[0] + red[1] + red[2] + red[3];
    const float scale = rsqrtf(tot / (float)DIM + 1e-6f);
    const int f = *fp, h = *hp, ww = *wp, gi = *gip;
    const int hw = h * ww;
    const int fi = s / hw;
    const int rem = s - fi * hw;
    const int hi = rem / ww;
    const int wi = rem - hi * ww;
    const int sf = gi * f;
    for (int p = tid; p < DIM / 2; p += 256) {
        int n = p >> 6, i = p & 63;
        int pos = (i < 22) ? (sf + fi) : (i < 43) ? hi : wi;
        float cs = freqs[pos * 128 + i * 2];
        float sn = freqs[pos * 128 + i * 2 + 1];
        int base = n * HD + 2 * i;
        float x0 = row[base] * scale * w[base];
        float x1 = row[base + 1] * scale * w[base + 1];
        row[base] = x0 * cs - x1 * sn;
        row[base + 1] = x0 * sn + x1 * cs;
    }
}

// ---------------- K+V prep: single-f16 RN, frag-linear KV records ----------
// V k-slots PERMUTED: slot s holds key (s>>1) + 16*(s&1), matching the
// interleaved packed-P layout. V reads vectorized (R12-verified): one key
// row per 8 threads, 4x float4 (was 8 scalar strided loads/thread).
__global__ __launch_bounds__(256) void kv_prep(
    const float* __restrict__ kws, const float* __restrict__ kcache,
    const float* __restrict__ vws, const float* __restrict__ vcache,
    _Float16* __restrict__ KV, int S, int NT, const int* __restrict__ gip)
{
    const int t = blockIdx.x, n = blockIdx.y;
    const int tid = threadIdx.x;
    const int lane = tid & 63;
    const int l16 = lane & 15, quad = lane >> 4;
    const int start = gip[0] * S;
    const int nk = start + S;
    _Float16* outk = KV + (size_t)(n * NT + t) * 8192;
    _Float16* outv = outk + 4096;
    // K part: frag-linear RN convert
    #pragma unroll
    for (int fi = 0; fi < 2; ++fi) {
        const int f = (tid >> 6) + fi * 4;
        const int ks = f >> 2, db = f & 3;
        const int j = t * KT + ks * 16 + l16;
        float4 a = make_float4(0,0,0,0), b = a;
        if (j < nk) {
            const float* src = (j < start) ? (kcache + (size_t)j * DIM)
                                           : (kws + (size_t)(j - start) * DIM);
            src += n * HD + db * 32 + quad * 8;
            a = *(const float4*)src;
            b = *(const float4*)(src + 4);
        }
        *(half8_t*)&outk[(f * 64 + lane) * 8] = cvt8rn(a, b);
    }
    // V part: row r = tid>>3, dims c0..c0+15, slot s with perm(s) = r
    {
        const int r  = tid >> 3;             // 0..31
        const int c0 = (tid & 7) * 16;       // 0..112
        const int key = t * KT + r;
        const int s  = (r & 15) * 2 + (r >> 4);
        float4 va = make_float4(0,0,0,0), vb = va, vc = va, vd = va;
        if (key < nk) {
            const float* src = (key < start) ? (vcache + (size_t)key * DIM)
                                             : (vws + (size_t)(key - start) * DIM);
            src += n * HD + c0;
            va = ((const float4*)src)[0];
            vb = ((const float4*)src)[1];
            vc = ((const float4*)src)[2];
            vd = ((const float4*)src)[3];
        }
        _Float16* o = outv + ((size_t)((c0 >> 4) * 64 + (s >> 3) * 16) * 8) + (s & 7);
        o[0]   = (_Float16)va.x; o[8]   = (_Float16)va.y;
        o[16]  = (_Float16)va.z; o[24]  = (_Float16)va.w;
        o[32]  = (_Float16)vb.x; o[40]  = (_Float16)vb.y;
        o[48]  = (_Float16)vb.z; o[56]  = (_Float16)vb.w;
        o[64]  = (_Float16)vc.x; o[72]  = (_Float16)vc.y;
        o[80]  = (_Float16)vc.z; o[88]  = (_Float16)vc.w;
        o[96]  = (_Float16)vd.x; o[104] = (_Float16)vd.y;
        o[112] = (_Float16)vd.z; o[120] = (_Float16)vd.w;
    }
}

// ---------------- MFMA flash attention (round-8 structure) ----------------
#define PSTRH 36
__global__ __launch_bounds__(256, 3) void attn_mfma(
    const float* __restrict__ q,
    const _Float16* __restrict__ KV,
    float* __restrict__ Op, float* __restrict__ Ml,
    int S, int NT, const int* __restrict__ gip)
{
    __shared__ __align__(16) _Float16 T[2][8192];   // [K 4096 | Vt 4096]
    __shared__ __align__(16) _Float16 Ph[4][2][16][PSTRH];

    const int nwg = gridDim.x;
    const int L = blockIdx.x;
    const int q8 = nwg >> 3, r8 = nwg & 7;
    const int xcd = L & 7, si = L >> 3;
    const int logical = (xcd < r8 ? xcd * (q8 + 1)
                                  : r8 * (q8 + 1) + (xcd - r8) * q8) + si;
    const int yb = (S + 127) >> 7;
    const int y = logical % yb;
    const int g = logical / yb;
    const int n = g % NH;
    const int ksp = g / NH;
    const int q0 = y * 128;

    const int tid = threadIdx.x;
    const int wave = tid >> 6;          // 0..3
    const int lane = tid & 63;
    const int l16 = lane & 15;
    const int quad = lane >> 4;
    const int start = gip[0] * S;
    const int nk = start + S;
    const int totTiles = (nk + KT - 1) / KT;
    const int tilesPer = (totTiles + KSPLIT - 1) / KSPLIT;
    const int t0 = ksp * tilesPer;
    const int t1 = min(t0 + tilesPer, totTiles);
    const float sc = 0.08838834764831845f;

    // ---- Q fragments: two 16-row q-subtiles per wave, single f16 RN ----
    half8_t qf[2][4];
    #pragma unroll
    for (int qs = 0; qs < 2; ++qs) {
        const int qrow = q0 + wave * 32 + qs * 16 + l16;
        const bool qv = qrow < S;
        const float* qp = q + (size_t)(qv ? qrow : 0) * DIM + n * HD + quad * 8;
        #pragma unroll
        for (int db = 0; db < 4; ++db) {
            float4 a = make_float4(0,0,0,0), b = a;
            if (qv) { a = *(const float4*)(qp + db * 32); b = *(const float4*)(qp + db * 32 + 4); }
            qf[qs][db] = cvt8rn(a, b);
        }
    }

    half8_t ones_f;
    {
        _Float16 ov = (l16 == 0) ? (_Float16)1.0f : (_Float16)0.0f;
        #pragma unroll
        for (int j = 0; j < 8; ++j) ones_f[j] = ov;
    }

    f32x4 O[2][9];
    #pragma unroll
    for (int qs = 0; qs < 2; ++qs)
        #pragma unroll
        for (int ds = 0; ds < 9; ++ds) O[qs][ds] = (f32x4){0.f, 0.f, 0.f, 0.f};

    const size_t tb = (size_t)n * NT;

    // ---- prologue: stage tile t0 into buf 0 (16 chunks / 4 waves = 4 each) ----
    if (t0 < t1) {
        const _Float16* gp = KV + (tb + t0) * 8192 + wave * 1024 + lane * 8;
        _Float16* d = &T[0][wave * 1024];
        gl2lds16(gp,              d);
        gl2lds16(gp + 512,        d + 512);
        gl2lds16(gp + 4096,       d + 4096);
        gl2lds16(gp + 4096 + 512, d + 4096 + 512);
    }

    int cur = 0;
    for (int t = t0; t < t1; ++t) {
        if (t + 1 < t1) {
            const _Float16* gp = KV + (tb + t + 1) * 8192 + wave * 1024 + lane * 8;
            _Float16* d = &T[cur ^ 1][wave * 1024];
            gl2lds16(gp,              d);
            gl2lds16(gp + 512,        d + 512);
            gl2lds16(gp + 4096,       d + 4096);
            gl2lds16(gp + 4096 + 512, d + 4096 + 512);
            asm volatile("s_waitcnt vmcnt(4)" ::: "memory");
        } else {
            asm volatile("s_waitcnt vmcnt(0)" ::: "memory");
        }
        __builtin_amdgcn_s_barrier();
        __builtin_amdgcn_sched_barrier(0);

        // ---- S = Q K^T; K frags shared by both q-subtiles ----
        f32x4 sacc[2][2];
        #pragma unroll
        for (int qs = 0; qs < 2; ++qs) {
            sacc[qs][0] = (f32x4){0.f, 0.f, 0.f, 0.f};
            sacc[qs][1] = (f32x4){0.f, 0.f, 0.f, 0.f};
        }
        const half8_t* kh8 = (const half8_t*)&T[cur][0];
        __builtin_amdgcn_s_setprio(1);
        #pragma unroll
        for (int ks = 0; ks < 2; ++ks) {
            #pragma unroll
            for (int db = 0; db < 4; ++db) {
                half8_t bh = kh8[(ks * 4 + db) * 64 + lane];
                sacc[0][ks] = __builtin_amdgcn_mfma_f32_16x16x32_f16(qf[0][db], bh, sacc[0][ks], 0, 0, 0);
                sacc[1][ks] = __builtin_amdgcn_mfma_f32_16x16x32_f16(qf[1][db], bh, sacc[1][ks], 0, 0, 0);
            }
        }
        __builtin_amdgcn_s_setprio(0);

        // ---- fixed-max softmax -> packed fp16 P (interleaved cols) ----
        const int k0 = t * KT;
        const bool v0 = (k0 + l16) < nk;
        const bool v1 = (k0 + 16 + l16) < nk;
        #pragma unroll
        for (int qs = 0; qs < 2; ++qs) {
            #pragma unroll
            for (int r = 0; r < 4; ++r) {
                float p0 = v0 ? __expf(sacc[qs][0][r] * sc - MFIX) : 0.f;
                float p1 = v1 ? __expf(sacc[qs][1][r] * sc - MFIX) : 0.f;
                half2_t pp;
                pp.x = (_Float16)p0;   // col 2*l16   -> key l16
                pp.y = (_Float16)p1;   // col 2*l16+1 -> key 16+l16
                *(half2_t*)&Ph[wave][qs][quad * 4 + r][2 * l16] = pp;
            }
        }

        // ---- P -> A-layout (wave-private; in-order DS pipe, no barrier) ----
        half8_t ph[2];
        #pragma unroll
        for (int qs = 0; qs < 2; ++qs)
            ph[qs] = *(const half8_t*)&Ph[wave][qs][l16][quad * 8];

        // ---- O += P V (+ l via ones-frag); V frags shared by both subtiles ----
        const half8_t* vt8 = (const half8_t*)&T[cur][4096];
        __builtin_amdgcn_s_setprio(1);
        #pragma unroll
        for (int ds = 0; ds < 8; ++ds) {
            half8_t vh = vt8[ds * 64 + lane];
            O[0][ds] = __builtin_amdgcn_mfma_f32_16x16x32_f16(ph[0], vh, O[0][ds], 0, 0, 0);
            O[1][ds] = __builtin_amdgcn_mfma_f32_16x16x32_f16(ph[1], vh, O[1][ds], 0, 0, 0);
        }
        O[0][8] = __builtin_amdgcn_mfma_f32_16x16x32_f16(ph[0], ones_f, O[0][8], 0, 0, 0);
        O[1][8] = __builtin_amdgcn_mfma_f32_16x16x32_f16(ph[1], ones_f, O[1][8], 0, 0, 0);
        __builtin_amdgcn_s_setprio(0);

        __builtin_amdgcn_sched_barrier(0);
        __builtin_amdgcn_s_barrier();
        cur ^= 1;
    }

    // ---- write partials ----
    #pragma unroll
    for (int qs = 0; qs < 2; ++qs)
        #pragma unroll
        for (int r = 0; r < 4; ++r) {
            const int row = q0 + wave * 32 + qs * 16 + quad * 4 + r;
            if (row < S) {
                float* op = Op + (((size_t)ksp * NH + n) * S + row) * HD + l16;
                #pragma unroll
                for (int ds = 0; ds < 8; ++ds) op[ds * 16] = O[qs][ds][r];
                if (l16 == 0)
                    Ml[((size_t)ksp * NH + n) * S + row] = O[qs][8][r];
            }
        }
}

// ------- merge split-K partials -> frag-linear hi/lo A-records for out-GEMM -------
__global__ __launch_bounds__(256) void attn_merge(
    const float* __restrict__ Op, const float* __restrict__ Ml,
    _Float16* __restrict__ oh, _Float16* __restrict__ ol, int S)
{
    const int idx = blockIdx.x * 256 + threadIdx.x;
    const int total = NH * S * HD / 2;
    if (idx >= total) return;
    const int d0 = (idx & 63) * 2;
    const int t = idx >> 6;
    const int row = t % S;
    const int n = t / S;
    float num0 = 0.f, num1 = 0.f, den = 0.f;
    #pragma unroll
    for (int ks = 0; ks < KSPLIT; ++ks) {
        const size_t base = ((size_t)ks * NH + n) * S + row;
        num0 += Op[base * HD + d0];
        num1 += Op[base * HD + d0 + 1];
        den += Ml[base];
    }
    const float v0 = num0 / den, v1 = num1 / den;
    half2_t h = pkrtz(v0, v1);
    half2_t l = pkrtz(v0 - (float)h.x, v1 - (float)h.y);
    const int k = n * HD + d0;
    const int mt = row >> 7, rr = row & 127;
    const int grp = rr >> 4, l16r = rr & 15;
    const int kk = k >> 5, quad = (k & 31) >> 3, jj = k & 7;
    const size_t a = ((size_t)(mt * KK48 + kk) * 4096)
                   + ((size_t)(grp * 64 + quad * 16 + l16r) * 8) + jj;
    *(half2_t*)&oh[a] = h;
    *(half2_t*)&ol[a] = l;
}

extern "C" void kernel_launch(void* const* d_in, const int* in_sizes, int n_in,
                              void* d_out, int out_size, void* d_ws, size_t ws_size,
                              hipStream_t stream)
{
    const float* x      = (const float*)d_in[0];
    const float* wq     = (const float*)d_in[1];
    const float* bq     = (const float*)d_in[2];
    const float* wk     = (const float*)d_in[3];
    const float* bk     = (const float*)d_in[4];
    const float* wv     = (const float*)d_in[5];
    const float* bv     = (const float*)d_in[6];
    const float* wo     = (const float*)d_in[7];
    const float* bo     = (const float*)d_in[8];
    const float* nqw    = (const float*)d_in[9];
    const float* nkw    = (const float*)d_in[10];
    const float* freqs  = (const float*)d_in[11];
    const float* kcache = (const float*)d_in[12];
    const float* vcache = (const float*)d_in[13];
    const int*   fp     = (const int*)d_in[14];
    const int*   hp     = (const int*)d_in[15];
    const int*   wp     = (const int*)d_in[16];
    const int*   gip    = (const int*)d_in[17];

    const int S = in_sizes[0] / DIM;
    const int total = in_sizes[12] / (NH * HD);
    const int NT = (total + KT - 1) / KT;
    const int MT = (S + 127) / 128;
    const size_t sd = (size_t)S * DIM;
    const size_t arec = (size_t)MT * KK48 * 4096;   // halfs per A-record buffer
    const size_t wrec = (size_t)12 * KK48 * 4096;   // halfs per W-record buffer

    char* p = (char*)d_ws;
    float* q  = (float*)p;            p += sd * 4;
    float* k  = (float*)p;            p += sd * 4;
    float* v  = (float*)p;            p += sd * 4;
    float* Op = (float*)p;            p += (size_t)KSPLIT * NH * S * HD * 4;
    float* Ml = (float*)p;            p += (size_t)KSPLIT * NH * S * 4;
    _Float16* KV  = (_Float16*)p;     p += (size_t)NH * NT * 8192 * 2;
    _Float16* xh  = (_Float16*)p;     p += arec * 2;
    _Float16* xl  = (_Float16*)p;     p += arec * 2;
    _Float16* oh  = (_Float16*)p;     p += arec * 2;
    _Float16* ol  = (_Float16*)p;     p += arec * 2;
    _Float16* wqh = (_Float16*)p;     p += wrec * 2;
    _Float16* wql = (_Float16*)p;     p += wrec * 2;
    _Float16* wkh = (_Float16*)p;     p += wrec * 2;
    _Float16* wkl = (_Float16*)p;     p += wrec * 2;
    _Float16* wvh = (_Float16*)p;     p += wrec * 2;
    _Float16* wvl = (_Float16*)p;     p += wrec * 2;
    _Float16* woh = (_Float16*)p;     p += wrec * 2;
    _Float16* wol = (_Float16*)p;     p += wrec * 2;
    float* out = (float*)d_out;

    const int an8 = (int)(arec / 8), wn8 = (int)(wrec / 8);

    cvt_a_fl<<<dim3((an8 + 255) / 256), dim3(256), 0, stream>>>(x, xh, xl, S, an8);
    cvt_w_fl<<<dim3((wn8 + 255) / 256, 4), dim3(256), 0, stream>>>(
        wq, wk, wv, wo, wqh, wql, wkh, wkl, wvh, wvl, woh, wol, wn8);

    // q,k: single-pass high-occupancy kernel (32 KB LDS, 4 blocks/CU)
    gemm_fl_s<<<dim3(24 * MT), dim3(256), 0, stream>>>(
        xh, wqh, wkh, bq, bk, q, k, S);
    // v: full hi/lo 3-pass
    gemm_fl<<<dim3(12 * MT), dim3(256), 0, stream>>>(
        xh, xl, wvh, wvl, bv, v, S);
    rms_rope2<<<dim3(S, 2), dim3(256), 0, stream>>>(q, k, nqw, nkw, freqs, fp, hp, wp, gip);
    kv_prep<<<dim3(NT, NH), dim3(256), 0, stream>>>(k, kcache, v, vcache, KV, S, NT, gip);
    {
        const int yb = (S + 127) / 128;
        const int nwg = NH * yb * KSPLIT;
        attn_mfma<<<dim3(nwg), dim3(256), 0, stream>>>(
            q, KV, Op, Ml, S, NT, gip);
    }
    attn_merge<<<dim3((NH * S * HD / 2 + 255) / 256), dim3(256), 0, stream>>>(Op, Ml, oh, ol, S);
    gemm_fl<<<dim3(12 * MT), dim3(256), 0, stream>>>(
        oh, ol, woh, wol, bo, out, S);
}